// Round 4
// baseline (52.295 us; speedup 1.0000x reference)
//
#include <hip/hip_runtime.h>

#define N_ATOMS  1536
#define FEAT     32
#define N_GAUSS  16
#define N_TYPES  10
#define MAXNBR   256
#define NTHREADS 256
#define NSTAGE   864   // 512 (W1 [g][f]) + 320 (embT [f][type]) + 32 (b1)

// ---------------- kernel 1: neighbor scan + message aggregation ----------------
__global__ __launch_bounds__(NTHREADS, 6) void gnn_agg_kernel(
    const float* __restrict__ xyz, const int* __restrict__ z,
    const float* __restrict__ emb, const float* __restrict__ W1,
    const float* __restrict__ b1,  const float* __restrict__ b3,
    float* __restrict__ x_out,     float* __restrict__ out)
{
    const int i    = blockIdx.x;
    const int tid  = threadIdx.x;
    const int lane = tid & 63;
    const int wid  = tid >> 6;

    __shared__ float sS[NSTAGE];
    float* sW1   = sS;          // [g][f]
    float* sEmbT = sS + 512;    // [f][type]
    float* sB1   = sS + 832;
    __shared__ int   s_nbr[MAXNBR];
    __shared__ float s_dist[MAXNBR];
    __shared__ float s_red[4 * FEAT];
    __shared__ int   s_cnt;

    // issue staging loads early; commit to LDS after the scan (latency hides)
    float rs[4];
    #pragma unroll
    for (int k = 0; k < 4; ++k) {
        int v = tid + k * NTHREADS;
        float val = 0.0f;
        if (v < 512)       val = W1[v];
        else if (v < 832)  { int u = v - 512; val = emb[(u % N_TYPES) * FEAT + (u / N_TYPES)]; }
        else if (v < NSTAGE) val = b1[v - 832];
        rs[k] = val;
    }

    if (tid == 0) s_cnt = 0;
    __syncthreads();

    const float xi = xyz[3*i+0], yi = xyz[3*i+1], zi = xyz[3*i+2];

    // ---- Phase A: N-scan, compact hits ----
    for (int j = tid; j < N_ATOMS; j += NTHREADS) {
        float dx = xyz[3*j+0] - xi;
        float dy = xyz[3*j+1] - yi;
        float dz = xyz[3*j+2] - zi;
        dx += (dx < -15.0f ? 30.0f : 0.0f) - (dx >= 15.0f ? 30.0f : 0.0f);
        dy += (dy < -15.0f ? 30.0f : 0.0f) - (dy >= 15.0f ? 30.0f : 0.0f);
        dz += (dz < -15.0f ? 30.0f : 0.0f) - (dz >= 15.0f ? 30.0f : 0.0f);
        float d2 = dx*dx + dy*dy + dz*dz;
        if (d2 < 25.0f && d2 > 0.0f) {
            int slot = atomicAdd(&s_cnt, 1);
            if (slot < MAXNBR) { s_nbr[slot] = j; s_dist[slot] = sqrtf(d2); }
        }
    }
    #pragma unroll
    for (int k = 0; k < 4; ++k) {
        int v = tid + k * NTHREADS;
        if (v < NSTAGE) sS[v] = rs[k];
    }
    __syncthreads();
    const int cnt = min(s_cnt, MAXNBR);

    // ---- Phase B: 8 lanes per pair, 4 features per lane ----
    const int fl   = tid & 7;    // feature group: features fl*4 .. fl*4+3
    const int slot = tid >> 3;   // pair slot 0..31
    float af[4] = {0.0f, 0.0f, 0.0f, 0.0f};

    for (int p = slot; p < cnt; p += 32) {
        const int   j  = s_nbr[p];
        const float d  = s_dist[p];
        const int   zj = z[j];
        float rbf[N_GAUSS];
        #pragma unroll
        for (int g = 0; g < N_GAUSS; ++g) {
            float t = d - (float)g * (5.0f / 15.0f);
            rbf[g] = __expf(-10.0f * t * t);
        }
        #pragma unroll
        for (int ff = 0; ff < 4; ++ff) {
            const int f = fl * 4 + ff;
            float s = sB1[f];
            #pragma unroll
            for (int g = 0; g < N_GAUSS; ++g) s = fmaf(rbf[g], sW1[g * FEAT + f], s);
            float t2 = __expf(-2.0f * fabsf(s));
            float th = copysignf((1.0f - t2) / (1.0f + t2), s);
            af[ff] = fmaf(th, sEmbT[f * N_TYPES + zj], af[ff]);
        }
    }

    // reduce across the 8 slots within each wave (xor bits 3,4,5)
    #pragma unroll
    for (int ff = 0; ff < 4; ++ff) {
        af[ff] += __shfl_xor(af[ff], 8,  64);
        af[ff] += __shfl_xor(af[ff], 16, 64);
        af[ff] += __shfl_xor(af[ff], 32, 64);
    }
    if (lane < 8) {
        #pragma unroll
        for (int ff = 0; ff < 4; ++ff) s_red[wid * FEAT + lane * 4 + ff] = af[ff];
    }
    __syncthreads();

    if (tid < FEAT) {
        float a = s_red[tid] + s_red[FEAT + tid] + s_red[2*FEAT + tid] + s_red[3*FEAT + tid];
        x_out[i * FEAT + tid] = a + sEmbT[tid * N_TYPES + z[i]];   // h + agg
    }
    if (i == 0 && tid == 0) out[0] = (float)N_ATOMS * b3[0];       // init (runs before k2)
}

// ---------------- kernel 2: per-atom MLP + global sum ----------------
__global__ __launch_bounds__(NTHREADS) void gnn_mlp_kernel(
    const float* __restrict__ x_in, const float* __restrict__ W2,
    const float* __restrict__ b2,   const float* __restrict__ W3,
    float* __restrict__ out)
{
    const int tid = threadIdx.x;
    const int a   = blockIdx.x * NTHREADS + tid;   // one atom per thread

    __shared__ float sW2[FEAT * FEAT];
    __shared__ float sB2[FEAT];
    __shared__ float sW3[FEAT];
    #pragma unroll
    for (int k = 0; k < 4; ++k) sW2[tid + k * NTHREADS] = W2[tid + k * NTHREADS];
    if (tid < FEAT) { sB2[tid] = b2[tid]; sW3[tid] = W3[tid]; }
    __syncthreads();

    float x[FEAT];
    #pragma unroll
    for (int k = 0; k < FEAT; ++k) x[k] = x_in[a * FEAT + k];

    float e = 0.0f;
    #pragma unroll
    for (int f = 0; f < FEAT; ++f) {
        float s = sB2[f];
        #pragma unroll
        for (int k = 0; k < FEAT; ++k) s = fmaf(x[k], sW2[k * FEAT + f], s);
        float u = s / (1.0f + __expf(-s));   // silu
        e = fmaf(u, sW3[f], e);
    }

    #pragma unroll
    for (int off = 32; off > 0; off >>= 1)
        e += __shfl_xor(e, off, 64);
    __shared__ float r[4];
    if ((tid & 63) == 0) r[tid >> 6] = e;
    __syncthreads();
    if (tid == 0) atomicAdd(out, r[0] + r[1] + r[2] + r[3]);
}

extern "C" void kernel_launch(void* const* d_in, const int* in_sizes, int n_in,
                              void* d_out, int out_size, void* d_ws, size_t ws_size,
                              hipStream_t stream) {
    const float* xyz = (const float*)d_in[0];
    const int*   z   = (const int*)  d_in[1];
    const float* emb = (const float*)d_in[2];
    const float* W1  = (const float*)d_in[3];
    const float* b1  = (const float*)d_in[4];
    const float* W2  = (const float*)d_in[5];
    const float* b2  = (const float*)d_in[6];
    const float* W3  = (const float*)d_in[7];
    const float* b3  = (const float*)d_in[8];
    float* out   = (float*)d_out;
    float* x_buf = (float*)d_ws;   // 1536*32 floats

    gnn_agg_kernel<<<N_ATOMS, NTHREADS, 0, stream>>>(xyz, z, emb, W1, b1, b3, x_buf, out);
    gnn_mlp_kernel<<<N_ATOMS / NTHREADS, NTHREADS, 0, stream>>>(x_buf, W2, b2, W3, out);
}

// Round 5
// 22.450 us; speedup vs baseline: 2.3294x; 2.3294x over previous
//
#include <hip/hip_runtime.h>

#define N_ATOMS  1536
#define FEAT     32
#define N_GAUSS  16
#define N_TYPES  10
#define MAXNBR   256
#define NTHREADS 256
#define NSTAGE   864   // 512 (W1 [g][f]) + 320 (embT [f][type]) + 32 (b1)

// ---------------- kernel 1: neighbor scan + message aggregation ----------------
// NOTE: no forced min-occupancy. (256,6) in R4 capped the allocator at 40 VGPRs
// and spilled ~256 B/thread -> 150 MB/dispatch of HBM scratch traffic (2x slower).
__global__ __launch_bounds__(NTHREADS, 2) void gnn_agg_kernel(
    const float* __restrict__ xyz, const int* __restrict__ z,
    const float* __restrict__ emb, const float* __restrict__ W1,
    const float* __restrict__ b1,  const float* __restrict__ b3,
    float* __restrict__ x_out,     float* __restrict__ out)
{
    const int i    = blockIdx.x;
    const int tid  = threadIdx.x;
    const int lane = tid & 63;
    const int wid  = tid >> 6;

    __shared__ float sS[NSTAGE];
    float* sW1   = sS;          // [g][f]
    float* sEmbT = sS + 512;    // [f][type]
    float* sB1   = sS + 832;
    __shared__ int   s_nbr[MAXNBR];
    __shared__ float s_dist[MAXNBR];
    __shared__ float s_red[4 * FEAT];
    __shared__ int   s_cnt;

    // issue staging loads early; commit to LDS after the scan (latency hides)
    float rs[4];
    #pragma unroll
    for (int k = 0; k < 4; ++k) {
        int v = tid + k * NTHREADS;
        float val = 0.0f;
        if (v < 512)       val = W1[v];
        else if (v < 832)  { int u = v - 512; val = emb[(u % N_TYPES) * FEAT + (u / N_TYPES)]; }
        else if (v < NSTAGE) val = b1[v - 832];
        rs[k] = val;
    }

    if (tid == 0) s_cnt = 0;
    __syncthreads();

    const float xi = xyz[3*i+0], yi = xyz[3*i+1], zi = xyz[3*i+2];

    // ---- Phase A: N-scan, compact hits ----
    for (int j = tid; j < N_ATOMS; j += NTHREADS) {
        float dx = xyz[3*j+0] - xi;
        float dy = xyz[3*j+1] - yi;
        float dz = xyz[3*j+2] - zi;
        dx += (dx < -15.0f ? 30.0f : 0.0f) - (dx >= 15.0f ? 30.0f : 0.0f);
        dy += (dy < -15.0f ? 30.0f : 0.0f) - (dy >= 15.0f ? 30.0f : 0.0f);
        dz += (dz < -15.0f ? 30.0f : 0.0f) - (dz >= 15.0f ? 30.0f : 0.0f);
        float d2 = dx*dx + dy*dy + dz*dz;
        if (d2 < 25.0f && d2 > 0.0f) {
            int slot = atomicAdd(&s_cnt, 1);
            if (slot < MAXNBR) { s_nbr[slot] = j; s_dist[slot] = sqrtf(d2); }
        }
    }
    #pragma unroll
    for (int k = 0; k < 4; ++k) {
        int v = tid + k * NTHREADS;
        if (v < NSTAGE) sS[v] = rs[k];
    }
    __syncthreads();
    const int cnt = min(s_cnt, MAXNBR);

    // ---- Phase B: 8 lanes per pair, 4 features per lane ----
    const int fl   = tid & 7;    // feature group: features fl*4 .. fl*4+3
    const int slot = tid >> 3;   // pair slot 0..31
    float af[4] = {0.0f, 0.0f, 0.0f, 0.0f};

    for (int p = slot; p < cnt; p += 32) {
        const int   j  = s_nbr[p];
        const float d  = s_dist[p];
        const int   zj = z[j];
        float rbf[N_GAUSS];
        #pragma unroll
        for (int g = 0; g < N_GAUSS; ++g) {
            float t = d - (float)g * (5.0f / 15.0f);
            rbf[g] = __expf(-10.0f * t * t);
        }
        #pragma unroll
        for (int ff = 0; ff < 4; ++ff) {
            const int f = fl * 4 + ff;
            float s = sB1[f];
            #pragma unroll
            for (int g = 0; g < N_GAUSS; ++g) s = fmaf(rbf[g], sW1[g * FEAT + f], s);
            float t2 = __expf(-2.0f * fabsf(s));
            float th = copysignf((1.0f - t2) / (1.0f + t2), s);
            af[ff] = fmaf(th, sEmbT[f * N_TYPES + zj], af[ff]);
        }
    }

    // reduce across the 8 slots within each wave (xor bits 3,4,5)
    #pragma unroll
    for (int ff = 0; ff < 4; ++ff) {
        af[ff] += __shfl_xor(af[ff], 8,  64);
        af[ff] += __shfl_xor(af[ff], 16, 64);
        af[ff] += __shfl_xor(af[ff], 32, 64);
    }
    if (lane < 8) {
        #pragma unroll
        for (int ff = 0; ff < 4; ++ff) s_red[wid * FEAT + lane * 4 + ff] = af[ff];
    }
    __syncthreads();

    if (tid < FEAT) {
        float a = s_red[tid] + s_red[FEAT + tid] + s_red[2*FEAT + tid] + s_red[3*FEAT + tid];
        x_out[i * FEAT + tid] = a + sEmbT[tid * N_TYPES + z[i]];   // h + agg
    }
    if (i == 0 && tid == 0) out[0] = (float)N_ATOMS * b3[0];       // init (runs before k2)
}

// ---------------- kernel 2: per-atom MLP + global sum ----------------
__global__ __launch_bounds__(NTHREADS) void gnn_mlp_kernel(
    const float* __restrict__ x_in, const float* __restrict__ W2,
    const float* __restrict__ b2,   const float* __restrict__ W3,
    float* __restrict__ out)
{
    const int tid = threadIdx.x;
    const int a   = blockIdx.x * NTHREADS + tid;   // one atom per thread

    __shared__ float sW2[FEAT * FEAT];
    __shared__ float sB2[FEAT];
    __shared__ float sW3[FEAT];
    #pragma unroll
    for (int k = 0; k < 4; ++k) sW2[tid + k * NTHREADS] = W2[tid + k * NTHREADS];
    if (tid < FEAT) { sB2[tid] = b2[tid]; sW3[tid] = W3[tid]; }
    __syncthreads();

    float x[FEAT];
    #pragma unroll
    for (int k = 0; k < FEAT; ++k) x[k] = x_in[a * FEAT + k];

    float e = 0.0f;
    #pragma unroll
    for (int f = 0; f < FEAT; ++f) {
        float s = sB2[f];
        #pragma unroll
        for (int k = 0; k < FEAT; ++k) s = fmaf(x[k], sW2[k * FEAT + f], s);
        float u = s / (1.0f + __expf(-s));   // silu
        e = fmaf(u, sW3[f], e);
    }

    #pragma unroll
    for (int off = 32; off > 0; off >>= 1)
        e += __shfl_xor(e, off, 64);
    __shared__ float r[4];
    if ((tid & 63) == 0) r[tid >> 6] = e;
    __syncthreads();
    if (tid == 0) atomicAdd(out, r[0] + r[1] + r[2] + r[3]);
}

extern "C" void kernel_launch(void* const* d_in, const int* in_sizes, int n_in,
                              void* d_out, int out_size, void* d_ws, size_t ws_size,
                              hipStream_t stream) {
    const float* xyz = (const float*)d_in[0];
    const int*   z   = (const int*)  d_in[1];
    const float* emb = (const float*)d_in[2];
    const float* W1  = (const float*)d_in[3];
    const float* b1  = (const float*)d_in[4];
    const float* W2  = (const float*)d_in[5];
    const float* b2  = (const float*)d_in[6];
    const float* W3  = (const float*)d_in[7];
    const float* b3  = (const float*)d_in[8];
    float* out   = (float*)d_out;
    float* x_buf = (float*)d_ws;   // 1536*32 floats

    gnn_agg_kernel<<<N_ATOMS, NTHREADS, 0, stream>>>(xyz, z, emb, W1, b1, b3, x_buf, out);
    gnn_mlp_kernel<<<N_ATOMS / NTHREADS, NTHREADS, 0, stream>>>(x_buf, W2, b2, W3, out);
}

// Round 6
// 20.499 us; speedup vs baseline: 2.5512x; 1.0952x over previous
//
#include <hip/hip_runtime.h>

#define N_ATOMS  1536
#define FEAT     32
#define N_GAUSS  16
#define MAXNBR   128   // ~30 expected neighbors; 128 = +18 sigma

// One wave (64 threads) per atom. No weight staging: all inputs (~25 KB)
// are L1-resident per CU after first touch; LDS holds only the neighbor queue.
// 1536 one-wave blocks -> 6 blocks/CU, entire grid co-resident in one round.
__global__ __launch_bounds__(64) void gnn_atom_kernel(
    const float* __restrict__ xyz, const int* __restrict__ z,
    const float* __restrict__ emb, const float* __restrict__ W1,
    const float* __restrict__ b1,  const float* __restrict__ W2,
    const float* __restrict__ b2,  const float* __restrict__ W3,
    float* __restrict__ e_atom)
{
    const int i   = blockIdx.x;
    const int tid = threadIdx.x;

    __shared__ int   s_nbr[MAXNBR];
    __shared__ float s_dist[MAXNBR];
    __shared__ float s_x[FEAT];
    __shared__ int   s_cnt;

    if (tid == 0) s_cnt = 0;
    __syncthreads();

    const float xi = xyz[3*i+0], yi = xyz[3*i+1], zi = xyz[3*i+2];

    // ---- Phase A: scan all atoms (24 iters), compact hits into LDS queue ----
    for (int j = tid; j < N_ATOMS; j += 64) {
        float dx = xyz[3*j+0] - xi;
        float dy = xyz[3*j+1] - yi;
        float dz = xyz[3*j+2] - zi;
        dx += (dx < -15.0f ? 30.0f : 0.0f) - (dx >= 15.0f ? 30.0f : 0.0f);
        dy += (dy < -15.0f ? 30.0f : 0.0f) - (dy >= 15.0f ? 30.0f : 0.0f);
        dz += (dz < -15.0f ? 30.0f : 0.0f) - (dz >= 15.0f ? 30.0f : 0.0f);
        float d2 = dx*dx + dy*dy + dz*dz;
        if (d2 < 25.0f && d2 > 0.0f) {
            int slot = atomicAdd(&s_cnt, 1);
            if (slot < MAXNBR) { s_nbr[slot] = j; s_dist[slot] = sqrtf(d2); }
        }
    }
    __syncthreads();
    const int cnt = min(s_cnt, MAXNBR);

    // ---- Phase B: 8 lanes per pair, 4 features per lane; g-outer (no rbf[]) ----
    const int fl   = tid & 7;    // feature group -> features fl*4 .. fl*4+3
    const int slot = tid >> 3;   // pair slot 0..7
    const float4 b1v = *(const float4*)&b1[fl*4];
    float af[4] = {0.0f, 0.0f, 0.0f, 0.0f};

    for (int p = slot; p < cnt; p += 8) {
        const int   j  = s_nbr[p];
        const float d  = s_dist[p];
        const int   zj = z[j];
        float s0 = b1v.x, s1 = b1v.y, s2 = b1v.z, s3 = b1v.w;
        #pragma unroll
        for (int g = 0; g < N_GAUSS; ++g) {
            float t = d - (float)g * (5.0f / 15.0f);
            float r = __expf(-10.0f * t * t);
            const float4 w = *(const float4*)&W1[g * FEAT + fl * 4];
            s0 = fmaf(r, w.x, s0); s1 = fmaf(r, w.y, s1);
            s2 = fmaf(r, w.z, s2); s3 = fmaf(r, w.w, s3);
        }
        const float4 hj = *(const float4*)&emb[zj * FEAT + fl * 4];
        float sv[4] = {s0, s1, s2, s3};
        float hv[4] = {hj.x, hj.y, hj.z, hj.w};
        #pragma unroll
        for (int ff = 0; ff < 4; ++ff) {
            float t2 = __expf(-2.0f * fabsf(sv[ff]));
            float th = copysignf((1.0f - t2) / (1.0f + t2), sv[ff]);
            af[ff] = fmaf(th, hv[ff], af[ff]);
        }
    }

    // reduce across the 8 slots (xor bits 3,4,5 of lane id)
    #pragma unroll
    for (int ff = 0; ff < 4; ++ff) {
        af[ff] += __shfl_xor(af[ff], 8,  64);
        af[ff] += __shfl_xor(af[ff], 16, 64);
        af[ff] += __shfl_xor(af[ff], 32, 64);
    }

    // lanes 0..7 publish x = h_i + agg
    if (tid < 8) {
        const float4 hi = *(const float4*)&emb[z[i] * FEAT + tid * 4];
        s_x[tid*4+0] = af[0] + hi.x;
        s_x[tid*4+1] = af[1] + hi.y;
        s_x[tid*4+2] = af[2] + hi.z;
        s_x[tid*4+3] = af[3] + hi.w;
    }
    __syncthreads();

    // ---- fused per-atom MLP on lanes 0..31: e_i = silu(x@W2+b2)@W3 ----
    float e = 0.0f;
    if (tid < FEAT) {
        float s = b2[tid];
        #pragma unroll
        for (int k = 0; k < FEAT; ++k)
            s = fmaf(s_x[k], W2[k * FEAT + tid], s);   // coalesced 128B row reads, L1-hit
        float u = s / (1.0f + __expf(-s));             // silu
        e = u * W3[tid];
    }
    e += __shfl_xor(e, 16, 64);
    e += __shfl_xor(e, 8,  64);
    e += __shfl_xor(e, 4,  64);
    e += __shfl_xor(e, 2,  64);
    e += __shfl_xor(e, 1,  64);
    if (tid == 0) e_atom[i] = e;
}

// ---- kernel 2: single-block sum of 1536 atom energies (no atomics) ----
__global__ __launch_bounds__(256) void gnn_sum_kernel(
    const float* __restrict__ e_atom, const float* __restrict__ b3,
    float* __restrict__ out)
{
    const int tid = threadIdx.x;
    float s = 0.0f;
    #pragma unroll
    for (int k = 0; k < N_ATOMS / 256; ++k) s += e_atom[tid + k * 256];
    #pragma unroll
    for (int off = 32; off > 0; off >>= 1)
        s += __shfl_xor(s, off, 64);
    __shared__ float r[4];
    if ((tid & 63) == 0) r[tid >> 6] = s;
    __syncthreads();
    if (tid == 0)
        out[0] = r[0] + r[1] + r[2] + r[3] + (float)N_ATOMS * b3[0];
}

extern "C" void kernel_launch(void* const* d_in, const int* in_sizes, int n_in,
                              void* d_out, int out_size, void* d_ws, size_t ws_size,
                              hipStream_t stream) {
    const float* xyz = (const float*)d_in[0];
    const int*   z   = (const int*)  d_in[1];
    const float* emb = (const float*)d_in[2];
    const float* W1  = (const float*)d_in[3];
    const float* b1  = (const float*)d_in[4];
    const float* W2  = (const float*)d_in[5];
    const float* b2  = (const float*)d_in[6];
    const float* W3  = (const float*)d_in[7];
    const float* b3  = (const float*)d_in[8];
    float* out    = (float*)d_out;
    float* e_atom = (float*)d_ws;   // 1536 floats

    gnn_atom_kernel<<<N_ATOMS, 64, 0, stream>>>(xyz, z, emb, W1, b1, W2, b2, W3, e_atom);
    gnn_sum_kernel<<<1, 256, 0, stream>>>(e_atom, b3, out);
}